// Round 9
// baseline (136.709 us; speedup 1.0000x reference)
//
#include <hip/hip_runtime.h>

// Non-selective SSM, A diagonal => exact per-state recurrence
//   h_i[t] = a_i h_i[t-1] + b_i u[t],  y[t] = sum_i c_i h_i[t]
// R9 = R7 structure with the LDS-pipe bottleneck halved:
//   scan in cb-units (g = a*g + cb*u), DPP pair pre-reduce (quad_perm 0xB1,
//   HW-proven in R7) -> stage only 32 pair-partials per t (half the bytes),
//   M[32][21] padded (odd stride: conflict-free writes, 2-way-free reads),
//   then R7's proven read + rowsum16 + float4-store epilogue.
// Only HW-proven primitives: readlane, quad_perm/row_ror DPP, b128 LDS, f32.

#define NCH   2048
#define LSEQ  2048
#define NQ    4
#define QL    512

#define WS_E    (2u*1024u*1024u)       // E_H [NQ][NCH][64] f32 = 2 MB
#define WS_NEED (4u*1024u*1024u)

__device__ inline float rlane(float v, int l){
    return __int_as_float(__builtin_amdgcn_readlane(__float_as_int(v), l));
}
template<int CTRL>
__device__ inline float dppadd(float v){
    int t = __builtin_amdgcn_mov_dpp(__float_as_int(v), CTRL, 0xF, 0xF, true);
    return v + __int_as_float(t);
}
// full sum over each 16-lane row: xor1, xor2 (quad_perm), ror4, ror8  [proven R7]
__device__ inline float rowsum16(float v){
    v = dppadd<0xB1>(v);    // quad_perm [1,0,3,2]
    v = dppadd<0x4E>(v);    // quad_perm [2,3,0,1]
    v = dppadd<0x124>(v);   // row_ror:4
    v = dppadd<0x128>(v);   // row_ror:8
    return v;
}

// ---------------- Phase A: chunk end-states in H-units ----------------
__global__ __launch_bounds__(256) void ssm_partialH(const float* __restrict__ u,
                                                    const float* __restrict__ A,
                                                    float* __restrict__ E)
{
    const int lane = threadIdx.x & 63;
    const int wv   = threadIdx.x >> 6;
    const int widx = blockIdx.x * 4 + wv;
    const int q    = widx & 3;
    const int ch   = widx >> 2;

    const float a = A[lane * 65];
    const float* __restrict__ base = u + (size_t)ch * LSEQ + q * QL;

    float H = 0.f;
    #pragma unroll
    for (int blk = 0; blk < 8; ++blk){
        float ur = base[blk * 64 + lane];
        #pragma unroll
        for (int tt = 0; tt < 64; ++tt)
            H = fmaf(a, H, rlane(ur, tt));
    }
    E[((size_t)q * NCH + ch) * 64 + lane] = H;
}

// ---------------- Phase C: combine + cb-unit scan + pair pre-reduce ----------------
__global__ __launch_bounds__(256) void ssm_scanC(const float* __restrict__ u,
                                                 const float* __restrict__ A,
                                                 const float* __restrict__ Bv,
                                                 const float* __restrict__ Cv,
                                                 const float* __restrict__ E,
                                                 float* __restrict__ y)
{
    __shared__ __align__(16) float Mt[4][32][21];   // 10752 B (odd 21-stride)

    const int lane = threadIdx.x & 63;
    const int wv   = threadIdx.x >> 6;
    const int widx = blockIdx.x * 4 + wv;
    const int q    = widx & 3;
    const int ch   = widx >> 2;

    const float a  = A[lane * 65];
    const float cb = Bv[lane] * Cv[lane];
    float a512 = a;
    #pragma unroll
    for (int s = 0; s < 9; ++s) a512 *= a512;   // a^512

    // inline combine (H-units), then convert to cb-units
    float Hc = 0.f;
    for (int qp = 0; qp < q; ++qp)
        Hc = fmaf(a512, Hc, E[((size_t)qp * NCH + ch) * 64 + lane]);
    float g = cb * Hc;

    const int sl = lane & 15, tg = lane >> 4;
    float* const Mw = &Mt[wv][0][0];
    const int wrow = (lane >> 1) * 21;              // pair-partial row (even lanes)

    const float* __restrict__ base = u + (size_t)ch * LSEQ + q * QL;
    float* __restrict__       yc   = y + (size_t)ch * LSEQ + q * QL;

    #pragma unroll
    for (int blk = 0; blk < 8; ++blk){
        float ur = base[blk * 64 + lane];
        #pragma unroll
        for (int sub = 0; sub < 4; ++sub){
            // 16 scan steps; pairsum (states 2m,2m+1) staged as float4 per 4t
            #pragma unroll
            for (int tb = 0; tb < 4; ++tb){
                float4 f4;
                #pragma unroll
                for (int k = 0; k < 4; ++k){
                    float uv = rlane(ur, sub * 16 + tb * 4 + k);
                    g = fmaf(a, g, cb * uv);
                    float p = dppadd<0xB1>(g);      // pairsum in both lanes
                    ((float*)&f4)[k] = p;
                }
                if ((lane & 1) == 0)
                    *(float4*)(Mw + wrow + tb * 4) = f4;
            }
            // read 2 quads (partials sl and sl+16), same-wave RAW -> lgkmcnt
            float4 q0 = *(const float4*)(Mw + sl * 21        + tg * 4);
            float4 q1 = *(const float4*)(Mw + (sl + 16) * 21 + tg * 4);
            float px = q0.x + q1.x, py = q0.y + q1.y;
            float pz = q0.z + q1.z, pw = q0.w + q1.w;
            // cross-partial reduce over sl (proven R7 epilogue)
            px = rowsum16(px); py = rowsum16(py);
            pz = rowsum16(pz); pw = rowsum16(pw);
            if (sl == 0){
                float4 o; o.x = px; o.y = py; o.z = pz; o.w = pw;
                *(float4*)(yc + blk * 64 + sub * 16 + tg * 4) = o;
            }
        }
    }
}

// ---------------- fallback: proven R1 scan ----------------
__global__ __launch_bounds__(256, 1) void ssm_r1(const float* __restrict__ u,
                                                 const float* __restrict__ A,
                                                 const float* __restrict__ Bv,
                                                 const float* __restrict__ Cv,
                                                 float* __restrict__ y)
{
    __shared__ float tile[4][64][68];
    const int wave = threadIdx.x >> 6;
    const int lane = threadIdx.x & 63;
    const int ch   = blockIdx.x * 4 + wave;

    const float* __restrict__ uc = u + (size_t)ch * LSEQ;
    float* __restrict__       yc = y + (size_t)ch * LSEQ;

    const float a  = A[lane * 65];
    const float cb = Bv[lane] * Cv[lane];

    float g = 0.0f;
    float (*tl)[68] = tile[wave];

    for (int t0 = 0; t0 < LSEQ; t0 += 64){
        float ur = uc[t0 + lane];
        #pragma unroll
        for (int t = 0; t < 64; ++t){
            g = fmaf(a, g, cb * rlane(ur, t));
            tl[t][lane] = g;
        }
        float ysum = 0.0f;
        #pragma unroll
        for (int i = 0; i < 64; i += 4){
            float4 v = *reinterpret_cast<const float4*>(&tl[lane][i]);
            ysum += (v.x + v.y) + (v.z + v.w);
        }
        yc[t0 + lane] = ysum;
    }
}

extern "C" void kernel_launch(void* const* d_in, const int* in_sizes, int n_in,
                              void* d_out, int out_size, void* d_ws, size_t ws_size,
                              hipStream_t stream)
{
    const float* u  = (const float*)d_in[0];
    const float* A  = (const float*)d_in[1];
    const float* Bv = (const float*)d_in[2];
    const float* Cv = (const float*)d_in[3];
    float*       yo = (float*)d_out;
    char*        ws = (char*)d_ws;

    if (ws_size >= WS_NEED){
        float* E = (float*)(ws + WS_E);
        ssm_partialH<<<NCH * NQ / 4, 256, 0, stream>>>(u, A, E);
        ssm_scanC<<<NCH * NQ / 4, 256, 0, stream>>>(u, A, Bv, Cv, E, yo);
    } else {
        ssm_r1<<<NCH / 4, 256, 0, stream>>>(u, A, Bv, Cv, yo);
    }
}